// Round 1
// baseline (55.716 us; speedup 1.0000x reference)
//
#include <hip/hip_runtime.h>

// Problem constants (compile-time from the reference module):
//   NPOSES=16, NBLOCKS=1024, ATOMS_PER_BLOCK=16, N_CNSTRS=3, IDEAL=4.0
//   _CNSTR_ATOMS[0] = {(0,0),(1,1)};  _CNSTR_ATOMS[1] = {(1,0),(2,1)};
//   _CNSTR_ATOMS[2] = {(0,0),(1,1)};  _CNSTR_POSE = {0,0,0}
//
// All constraints are pose 0, and constraints 0 and 2 are identical, so:
//   out[0] = 2*(||c[bco[0]+0] - c[bco[1]+1]|| - 4)^2
//          +   (||c[bco[1]+0] - c[bco[2]+1]|| - 4)^2
//   out[1..15] = 0
//
// Device work is ~12 float loads behind one dependent int-load round trip;
// the measured time is expected to be dominated by launch overhead.

#define NPOSES 16
#define NBLOCKS 1024
#define ATOMS_PER_BLOCK 16

__global__ void cnstr_score_kernel(const float* __restrict__ coords,
                                   const int* __restrict__ bco,
                                   float* __restrict__ out) {
    const int t = threadIdx.x;
    float val = 0.0f;

    if (t == 0) {
        // Round trip 1: the three distinct block offsets (independent loads,
        // issued together -> one wait).
        const int o0 = bco[0];
        const int o1 = bco[1];
        const int o2 = bco[2];

        // Round trip 2: the four distinct atom coordinates (pose 0 base).
        const float* pa = coords + (long)(o0 + 0) * 3;  // cnstr A atom 0
        const float* pb = coords + (long)(o1 + 1) * 3;  // cnstr A atom 1
        const float* pc = coords + (long)(o1 + 0) * 3;  // cnstr B atom 0
        const float* pd = coords + (long)(o2 + 1) * 3;  // cnstr B atom 1

        const float ax = pa[0], ay = pa[1], az = pa[2];
        const float bx = pb[0], by = pb[1], bz = pb[2];
        const float cx = pc[0], cy = pc[1], cz = pc[2];
        const float ex = pd[0], ey = pd[1], ez = pd[2];

        const float d0x = ax - bx, d0y = ay - by, d0z = az - bz;
        const float d1x = cx - ex, d1y = cy - ey, d1z = cz - ez;

        const float s0 = sqrtf(d0x * d0x + d0y * d0y + d0z * d0z) - 4.0f;
        const float s1 = sqrtf(d1x * d1x + d1y * d1y + d1z * d1z) - 4.0f;

        // constraint 0 and 2 are identical -> weight 2; constraint 1 -> weight 1
        val = 2.0f * s0 * s0 + s1 * s1;
    }

    // one coalesced 16-lane store; lanes 1..15 write the zero poses
    if (t < NPOSES) out[t] = val;
}

extern "C" void kernel_launch(void* const* d_in, const int* in_sizes, int n_in,
                              void* d_out, int out_size, void* d_ws, size_t ws_size,
                              hipStream_t stream) {
    const float* coords = (const float*)d_in[0];
    const int* block_coord_offset = (const int*)d_in[1];
    float* out = (float*)d_out;
    cnstr_score_kernel<<<1, 64, 0, stream>>>(coords, block_coord_offset, out);
}